// Round 7
// baseline (354.611 us; speedup 1.0000x reference)
//
#include <hip/hip_runtime.h>
#include <hip/hip_bf16.h>
#include <stdint.h>

typedef unsigned int u32;
typedef unsigned short u16;
typedef __attribute__((ext_vector_type(8))) short bf16x8;
typedef __attribute__((ext_vector_type(4))) float f32x4;

__device__ __forceinline__ float u16tof(u16 u){ return __uint_as_float(((u32)u) << 16); }
__device__ __forceinline__ float lo16(u32 v){ return __uint_as_float(v << 16); }
__device__ __forceinline__ float hi16(u32 v){ return __uint_as_float(v & 0xffff0000u); }
__device__ __forceinline__ u16 ftobf(float f){
  u32 b = __float_as_uint(f);
  return (u16)((b + 0x7FFFu + ((b >> 16) & 1u)) >> 16);
}
__device__ __forceinline__ u32 pack2(float a, float b){
  return (u32)ftobf(a) | ((u32)ftobf(b) << 16);
}
__device__ __forceinline__ float ldf(const void* p, int i, int isbf){
  return isbf ? u16tof(((const u16*)p)[i]) : ((const float*)p)[i];
}

__device__ __forceinline__ void acc8(float* a, uint4 v, float mk){
  a[0] = fmaf(lo16(v.x), mk, a[0]);
  a[1] = fmaf(hi16(v.x), mk, a[1]);
  a[2] = fmaf(lo16(v.y), mk, a[2]);
  a[3] = fmaf(hi16(v.y), mk, a[3]);
  a[4] = fmaf(lo16(v.z), mk, a[4]);
  a[5] = fmaf(hi16(v.z), mk, a[5]);
  a[6] = fmaf(lo16(v.w), mk, a[6]);
  a[7] = fmaf(hi16(v.w), mk, a[7]);
}

// async global->LDS, 16B per lane. Global src is PER-LANE; LDS dst is wave-uniform
// base + lane*16 (hardware rule). Counted by vmcnt, costs no VGPRs.
__device__ __forceinline__ void async16(const u16* g, const u16* l){
  __builtin_amdgcn_global_load_lds(
      (const __attribute__((address_space(1))) u32*)(uintptr_t)g,
      (__attribute__((address_space(3))) u32*)(uintptr_t)l,
      16, 0, 0);
}

// ---- zero the degree array ----
__global__ __launch_bounds__(256) void k_zero(int* __restrict__ deg, int N){
  const int i = blockIdx.x * 256 + threadIdx.x;
  if (i < N) deg[i] = 0;
}

// ---- fused prep. Block ranges (blockIdx-uniform branch):
//  [0, L] weights; [L+1, +goffB) goff; rest: deg count (global atomics) ----
__global__ __launch_bounds__(256) void k_prep(const void* __restrict__ gw, const void* __restrict__ l1w,
                                              u16* __restrict__ Wf, int L, int goffB,
                                              const int* __restrict__ batch, int* __restrict__ goff,
                                              int N, int G,
                                              const int* __restrict__ dst, int* __restrict__ deg,
                                              int nE, int chunk, int* __restrict__ flag){
  __shared__ int sh[1];
  const int b = blockIdx.x;
  const int t = threadIdx.x;

  if (b >= L + 1 + goffB){                   // ---- degree count, global atomics
    const int blk = b - (L + 1 + goffB);
    const int e0 = blk * chunk, e1 = min(e0 + chunk, nE);
    for (int e = e0 + t; e < e1; e += 256) atomicAdd(&deg[dst[e]], 1);
    return;
  }
  if (b >= L + 1){                           // ---- goff build
    const int i = (b - (L + 1)) * 256 + t;
    if (i >= N) return;
    const int bt = batch[i];
    const int prev = (i == 0) ? -1 : batch[i - 1];
    for (int g = prev + 1; g <= bt; ++g) goff[g] = i;
    if (i == N - 1){ for (int g = bt + 1; g <= G; ++g) goff[g] = N; }
    return;
  }
  // ---- weight prep (full dtype detect)
  if (t == 0) sh[0] = 0;
  __syncthreads();
  int local = 0;
  for (int i = t; i < 4096; i += 256){
    u32 e = (((const u32*)gw)[i] >> 7) & 0xFFu;
    if (e >= 100u && e < 127u) local++;
  }
  atomicAdd(&sh[0], local);
  __syncthreads();
  const int isbf = (sh[0] > 2048) ? 1 : 0;
  if (b == 0 && t == 0) *flag = isbf;

  const void* src = (b < L) ? gw : l1w;
  const int sbase = (b < L) ? b * 16384 : 0;
  u16* dstp = Wf + (size_t)b * 16384;
  for (int g = t; g < 2048; g += 256){
    const int tt = g >> 8, ks = (g >> 6) & 3, lane = g & 63;
    const int n = tt * 16 + (lane & 15);
    const int k0 = ks * 32 + ((lane >> 4) << 3);
    u16* d = dstp + (size_t)g * 8;
    #pragma unroll
    for (int j = 0; j < 8; ++j){
      d[j] = ftobf(ldf(src, sbase + (k0 + j) * 128 + n, isbf));
    }
  }
}

// ---- scan A: per-block exclusive scan of deg -> boff (partial) + block sums ----
__global__ __launch_bounds__(256) void k_scanA(const int* __restrict__ deg, int* __restrict__ boff,
                                               int* __restrict__ bsum, int N){
  __shared__ int sm[256];
  const int t = threadIdx.x;
  const int i = blockIdx.x * 256 + t;
  const int d = (i < N) ? deg[i] : 0;
  sm[t] = d; __syncthreads();
  for (int off = 1; off < 256; off <<= 1){
    int a = (t >= off) ? sm[t - off] : 0;
    __syncthreads();
    sm[t] += a;
    __syncthreads();
  }
  if (i < N) boff[i] = sm[t] - d;            // local exclusive
  if (t == 255) bsum[blockIdx.x] = sm[255];
}

// ---- scan B: 1-block exclusive scan of block sums (nblk <= 512) ----
__global__ __launch_bounds__(512) void k_scanB(int* __restrict__ bsum, int nblk){
  __shared__ int sm[512];
  const int t = threadIdx.x;
  const int v = (t < nblk) ? bsum[t] : 0;
  sm[t] = v; __syncthreads();
  for (int off = 1; off < 512; off <<= 1){
    int a = (t >= off) ? sm[t - off] : 0;
    __syncthreads();
    sm[t] += a;
    __syncthreads();
  }
  if (t < nblk) bsum[t] = sm[t] - v;
}

// ---- scan C: finalize boff, init cur, compute dinv ----
__global__ __launch_bounds__(256) void k_scanC(const int* __restrict__ deg, int* __restrict__ boff,
                                               const int* __restrict__ bsum, int* __restrict__ cur,
                                               float* __restrict__ dinv, int N, int nE){
  const int t = threadIdx.x;
  const int i = blockIdx.x * 256 + t;
  if (i < N){
    const int b = boff[i] + bsum[blockIdx.x];
    boff[i] = b;
    cur[i] = b;
    dinv[i] = rsqrtf((float)deg[i] + 1.0f);
  }
  if (blockIdx.x == 0 && t == 0) boff[N] = nE;
}

// ---- direct fill: eid[pos] = src, pos via per-dst atomic cursor ----
__global__ __launch_bounds__(256) void k_fill(const int* __restrict__ src, const int* __restrict__ dst,
                                              int* __restrict__ cur, int* __restrict__ eid,
                                              int nE, int chunk){
  const int blk = blockIdx.x, t = threadIdx.x;
  const int e0 = blk * chunk, e1 = min(e0 + chunk, nE);
  for (int e = e0 + t; e < e1; e += 256){
    const int pos = atomicAdd(&cur[dst[e]], 1);
    eid[pos] = src[e];
  }
}

// ---- dense matmul: T = (A @ W) * dinv, bf16 out (64 rows/block, W in LDS).
//      cvtin=1: A may be fp32 (when *fl==0) -> convert in-register (kills cvt pass). ----
__global__ __launch_bounds__(256) void k_mm(const void* __restrict__ X, const u16* __restrict__ Wf,
                                            const float* __restrict__ dinv, u16* __restrict__ T,
                                            int n, int cvtin, const int* __restrict__ fl){
  __shared__ u16 smw[16384];
  const int isbf = *fl;
  const int fp32in = cvtin && !isbf;
  {
    const uint4* s = (const uint4*)Wf;
    uint4* d = (uint4*)smw;
    for (int i = threadIdx.x; i < 2048; i += 256) d[i] = s[i];
  }
  __syncthreads();

  const int wave = threadIdx.x >> 6, lane = threadIdx.x & 63;
  const int m0 = blockIdx.x * 64 + wave * 16;
  int arow = m0 + (lane & 15); if (arow > n - 1) arow = n - 1;
  const int koff = (lane >> 4) << 3;

  f32x4 acc[8];
  #pragma unroll
  for (int t = 0; t < 8; ++t) acc[t] = (f32x4){0.f, 0.f, 0.f, 0.f};

  #pragma unroll
  for (int ks = 0; ks < 4; ++ks){
    bf16x8 a;
    if (fp32in){
      const float* ap = (const float*)X + (size_t)arow * 128 + koff + ks * 32;
      const float4 f0 = *(const float4*)ap;
      const float4 f1 = *(const float4*)(ap + 4);
      a = (bf16x8){(short)ftobf(f0.x), (short)ftobf(f0.y), (short)ftobf(f0.z), (short)ftobf(f0.w),
                   (short)ftobf(f1.x), (short)ftobf(f1.y), (short)ftobf(f1.z), (short)ftobf(f1.w)};
    } else {
      a = *(const bf16x8*)((const u16*)X + (size_t)arow * 128 + koff + ks * 32);
    }
    #pragma unroll
    for (int t = 0; t < 8; ++t){
      const bf16x8 b = *(const bf16x8*)(smw + (size_t)(((t * 4 + ks) * 64 + lane) * 8));
      acc[t] = __builtin_amdgcn_mfma_f32_16x16x32_bf16(a, b, acc[t], 0, 0, 0);
    }
  }
  __syncthreads();

  const int quad = lane >> 4, col0 = lane & 15;
  float dv[4];
  #pragma unroll
  for (int r = 0; r < 4; ++r){
    const int row = m0 + quad * 4 + r;
    dv[r] = (row < n) ? dinv[row] : 0.f;
  }
  u16* my = smw + wave * 2112;
  #pragma unroll
  for (int t = 0; t < 8; ++t){
    #pragma unroll
    for (int r = 0; r < 4; ++r){
      my[(quad * 4 + r) * 132 + t * 16 + col0] = ftobf(acc[t][r] * dv[r]);
    }
  }
  #pragma unroll
  for (int i = 0; i < 4; ++i){
    const int row = i * 4 + (lane >> 4);
    const int grow = m0 + row;
    const int c8 = (lane & 15) * 8;
    if (grow < n){
      const u16* s = &my[row * 132 + c8];
      uint2 lo = *(const uint2*)(s);
      uint2 hi = *(const uint2*)(s + 4);
      *(uint4*)&T[(size_t)grow * 128 + c8] = make_uint4(lo.x, lo.y, hi.x, hi.y);
    }
  }
}

// ---- PURE gather kernel: H = (gather(Tin) + b[layer]) [relu], bf16 out.
//      16 nodes/block, 256 threads, LDS-ring async pipeline (measured 2.44 TB/s). ----
__global__ __launch_bounds__(256) void k_gath(const u16* __restrict__ Tin, const int* __restrict__ boff,
                                              const int* __restrict__ eid, const float* __restrict__ dinv,
                                              const void* __restrict__ bias, int layer, int dorelu,
                                              u16* __restrict__ Hout, int n, const int* __restrict__ fl){
  __shared__ u16 ring[4][4][512];   // [wave][slot][1KB]
  __shared__ int seid[512];
  __shared__ int sboff[17];
  const int isbf = *fl;
  const int tid = threadIdx.x;
  const int wave = tid >> 6, lane = tid & 63;
  const int sub = lane >> 4, l16 = lane & 15;
  const int m0 = blockIdx.x * 16;

  const int e0 = boff[m0];
  const int e1 = boff[min(m0 + 16, n)];
  const int len = e1 - e0;
  const int inlds = (len <= 512);
  if (tid < 17) sboff[tid] = boff[min(m0 + tid, n)];
  if (inlds){ for (int i = tid; i < len; i += 256) seid[i] = eid[e0 + i]; }
  __syncthreads();

  const int wsub = wave * 4 + sub;
  const int node = m0 + wsub;
  const int js = sboff[wsub];
  const int d  = sboff[wsub + 1] - js;

  float a[8];
  #pragma unroll
  for (int k = 0; k < 8; ++k) a[k] = 0.f;
  if (node < n){
    const uint4 sv = ((const uint4*)(Tin + (size_t)node * 128))[l16];
    acc8(a, sv, 1.f);
  }

  int T = 0;
  #pragma unroll
  for (int s2 = 0; s2 < 4; ++s2){
    const int dd = sboff[wave * 4 + s2 + 1] - sboff[wave * 4 + s2];
    T = (dd > T) ? dd : T;
  }

  if (inlds){
    const int jloc = js - e0;
    const int jlast = jloc + ((d > 0) ? (d - 1) : 0);
    const u16* base = Tin + (size_t)l16 * 8;
    u16* slot = &ring[wave][0][0];
    #pragma unroll
    for (int t = 0; t < 4; ++t){
      if (t < T){
        const int idx = (d > 0) ? seid[(t < d) ? (jloc + t) : jlast] : 0;
        async16(base + (size_t)idx * 128, slot + (t & 3) * 512);
      }
    }
    int t = 0;
    for (; t + 4 <= T; ++t){
      asm volatile("s_waitcnt vmcnt(3)" ::: "memory");
      const uint4 v = *(const uint4*)(slot + (t & 3) * 512 + lane * 8);
      acc8(a, v, (t < d) ? 1.f : 0.f);
      const int tn = t + 4;
      if (tn < T){
        const int idx = (d > 0) ? seid[(tn < d) ? (jloc + tn) : jlast] : 0;
        async16(base + (size_t)idx * 128, slot + (tn & 3) * 512);
      }
    }
    for (; t < T; ++t){
      const int rem = T - t - 1;
      if (rem >= 2)      asm volatile("s_waitcnt vmcnt(2)" ::: "memory");
      else if (rem == 1) asm volatile("s_waitcnt vmcnt(1)" ::: "memory");
      else               asm volatile("s_waitcnt vmcnt(0)" ::: "memory");
      const uint4 v = *(const uint4*)(slot + (t & 3) * 512 + lane * 8);
      acc8(a, v, (t < d) ? 1.f : 0.f);
    }
  } else {
    for (int j = js; j < js + d; ++j){
      const uint4 v = ((const uint4*)(Tin + (size_t)eid[j] * 128))[l16];
      acc8(a, v, 1.f);
    }
  }

  if (node < n){
    const float di = dinv[node];
    const int bb = layer * 128 + l16 * 8;
    float h[8];
    #pragma unroll
    for (int k = 0; k < 8; ++k){
      h[k] = fmaf(a[k], di, ldf(bias, bb + k, isbf));
      if (dorelu) h[k] = fmaxf(h[k], 0.f);
    }
    uint4 o;
    o.x = pack2(h[0], h[1]); o.y = pack2(h[2], h[3]); o.z = pack2(h[4], h[5]); o.w = pack2(h[6], h[7]);
    *(uint4*)&Hout[(size_t)node * 128 + l16 * 8] = o;
  }
}

// ---- dense MLP head: s = relu(H @ W1 + b1) . w2 + b2, masked (64 rows/block) ----
__global__ __launch_bounds__(256) void k_head(const u16* __restrict__ H, const u16* __restrict__ Wf,
                                              const void* __restrict__ b1, const void* __restrict__ w2,
                                              const void* __restrict__ b2, const int* __restrict__ mask,
                                              float* __restrict__ s, int n, const int* __restrict__ fl){
  __shared__ u16 smw[16384];
  __shared__ float sred[4][16];
  const int isbf = *fl;
  {
    const uint4* sp = (const uint4*)Wf;
    uint4* d = (uint4*)smw;
    for (int i = threadIdx.x; i < 2048; i += 256) d[i] = sp[i];
  }
  __syncthreads();

  const int wave = threadIdx.x >> 6, lane = threadIdx.x & 63;
  const int m0 = blockIdx.x * 64 + wave * 16;
  int arow = m0 + (lane & 15); if (arow > n - 1) arow = n - 1;
  const u16* aptr = H + (size_t)arow * 128 + ((lane >> 4) << 3);

  f32x4 acc[8];
  #pragma unroll
  for (int t = 0; t < 8; ++t) acc[t] = (f32x4){0.f, 0.f, 0.f, 0.f};
  #pragma unroll
  for (int ks = 0; ks < 4; ++ks){
    const bf16x8 a = *(const bf16x8*)(aptr + ks * 32);
    #pragma unroll
    for (int t = 0; t < 8; ++t){
      const bf16x8 b = *(const bf16x8*)(smw + (size_t)(((t * 4 + ks) * 64 + lane) * 8));
      acc[t] = __builtin_amdgcn_mfma_f32_16x16x32_bf16(a, b, acc[t], 0, 0, 0);
    }
  }

  const int quad = lane >> 4, col0 = lane & 15;
  float p[4] = {0.f, 0.f, 0.f, 0.f};
  #pragma unroll
  for (int t = 0; t < 8; ++t){
    const int col = t * 16 + col0;
    const float bv = ldf(b1, col, isbf);
    const float wv = ldf(w2, col, isbf);
    #pragma unroll
    for (int r = 0; r < 4; ++r){
      p[r] = fmaf(fmaxf(acc[t][r] + bv, 0.f), wv, p[r]);
    }
  }
  #pragma unroll
  for (int k = 1; k < 16; k <<= 1){
    #pragma unroll
    for (int r = 0; r < 4; ++r) p[r] += __shfl_xor(p[r], k);
  }
  if (col0 == 0){
    #pragma unroll
    for (int r = 0; r < 4; ++r) sred[wave][quad * 4 + r] = p[r];
  }
  __syncthreads();
  if (threadIdx.x < 64){
    const int row = blockIdx.x * 64 + threadIdx.x;
    if (row < n){
      const int w = threadIdx.x >> 4, idx = threadIdx.x & 15;
      float sc = sred[w][idx] + ldf(b2, 0, isbf);
      if (mask[row] == 0) sc = -1e9f;
      s[row] = sc;
    }
  }
}

// ---- per-graph softmax ----
__global__ __launch_bounds__(256) void k_gsm(const float* __restrict__ s, const int* __restrict__ goff,
                                             void* __restrict__ out, int G, const int* __restrict__ fl){
  const int g = blockIdx.x * 4 + (threadIdx.x >> 6);
  if (g >= G) return;
  const int lane = threadIdx.x & 63;
  const int i0 = goff[g], i1 = goff[g + 1];
  if (i0 >= i1) return;
  float m = -3.4e38f;
  for (int j = i0 + lane; j < i1; j += 64) m = fmaxf(m, s[j]);
  #pragma unroll
  for (int k = 32; k; k >>= 1) m = fmaxf(m, __shfl_xor(m, k));
  float zz = 0.f;
  for (int j = i0 + lane; j < i1; j += 64) zz += expf(s[j] - m);
  #pragma unroll
  for (int k = 32; k; k >>= 1) zz += __shfl_xor(zz, k);
  const float rz = 1.f / zz;
  const int isbf = *fl;
  for (int j = i0 + lane; j < i1; j += 64){
    const float v = expf(s[j] - m) * rz;
    if (isbf) ((u16*)out)[j] = ftobf(v);
    else      ((float*)out)[j] = v;
  }
}

extern "C" void kernel_launch(void* const* d_in, const int* in_sizes, int n_in,
                              void* d_out, int out_size, void* d_ws, size_t ws_size,
                              hipStream_t stream){
  const void* x    = d_in[0];
  const int* ei    = (const int*)d_in[1];
  const int* batch = (const int*)d_in[2];
  const int* mask  = (const int*)d_in[3];
  const void* gw   = d_in[4];
  const void* gb   = d_in[5];
  const void* l1w  = d_in[6];
  const void* l1b  = d_in[7];
  const void* l2w  = d_in[8];
  const void* l2b  = d_in[9];

  const int N = in_sizes[2];        // <= 131072 (scanB capacity 512 blocks of 256)
  const int E = in_sizes[1] / 2;
  const int D = 128;
  const int L = in_sizes[4] / (D * D);
  const int G = 1000;   // from reference; not derivable from sizes

  char* p = (char*)d_ws;
  u16*  Hb    = (u16*)p;   p += (size_t)N * D * sizeof(u16);   // H ping
  u16*  Tb    = (u16*)p;   p += (size_t)N * D * sizeof(u16);   // T pong
  u16*  Wf    = (u16*)p;   p += (size_t)(L + 1) * D * D * sizeof(u16);
  float* dinv = (float*)p; p += (size_t)N * sizeof(float);
  float* sbuf = (float*)p; p += (size_t)N * sizeof(float);
  int*  boff  = (int*)p;   p += (size_t)(N + 1) * sizeof(int);
  int*  eid   = (int*)p;   p += (size_t)E * sizeof(int);
  int*  goff  = (int*)p;   p += (size_t)(G + 1) * sizeof(int);
  int*  deg   = (int*)p;   p += (size_t)N * sizeof(int);
  int*  cur   = (int*)p;   p += (size_t)N * sizeof(int);
  int*  bsum  = (int*)p;   p += 512 * sizeof(int);
  int*  flag  = (int*)p;   p += 256;

  const int* srcp = ei;
  const int* dstp = ei + E;

  const int mmg   = (N + 63) / 64;
  const int fg    = (N + 15) / 16;
  const int goffB = (N + 255) / 256;
  const int scanG = (N + 255) / 256;
  const int chunk = (E + 255) / 256;

  // ---- prep: deg-zero; {weights | goff | deg-count}; scan; fill ----
  k_zero<<<scanG, 256, 0, stream>>>(deg, N);
  k_prep<<<(L + 1) + goffB + 256, 256, 0, stream>>>(gw, l1w, Wf, L, goffB,
                                                    batch, goff, N, G, dstp, deg, E, chunk, flag);
  k_scanA<<<scanG, 256, 0, stream>>>(deg, boff, bsum, N);
  k_scanB<<<1, 512, 0, stream>>>(bsum, scanG);
  k_scanC<<<scanG, 256, 0, stream>>>(deg, boff, bsum, cur, dinv, N, E);
  k_fill<<<256, 256, 0, stream>>>(srcp, dstp, cur, eid, E, chunk);

  // ---- layer 0: T0 = (x @ W0)*dinv  (reads fp32 x directly when needed) ----
  k_mm<<<mmg, 256, 0, stream>>>(x, Wf, dinv, Tb, N, 1, flag);
  // H0 = relu(gather(T0)+b0) ; T1 = (H0 @ W1)*dinv
  k_gath<<<fg, 256, 0, stream>>>(Tb, boff, eid, dinv, gb, 0, 1, Hb, N, flag);
  k_mm<<<mmg, 256, 0, stream>>>(Hb, Wf + (size_t)1 * D * D, dinv, Tb, N, 0, flag);
  // H1 = relu(gather(T1)+b1) ; T2 = (H1 @ W2)*dinv
  k_gath<<<fg, 256, 0, stream>>>(Tb, boff, eid, dinv, gb, 1, 1, Hb, N, flag);
  k_mm<<<mmg, 256, 0, stream>>>(Hb, Wf + (size_t)2 * D * D, dinv, Tb, N, 0, flag);
  // H2 = gather(T2)+b2 (no relu) ; head ; softmax
  k_gath<<<fg, 256, 0, stream>>>(Tb, boff, eid, dinv, gb, 2, 0, Hb, N, flag);
  k_head<<<mmg, 256, 0, stream>>>(Hb, Wf + (size_t)L * D * D, l1b, l2w, l2b, mask, sbuf, N, flag);
  k_gsm<<<(G + 3) / 4, 256, 0, stream>>>(sbuf, goff, d_out, G, flag);
}

// Round 8
// 312.273 us; speedup vs baseline: 1.1356x; 1.1356x over previous
//
#include <hip/hip_runtime.h>
#include <hip/hip_bf16.h>
#include <stdint.h>

typedef unsigned int u32;
typedef unsigned short u16;
typedef __attribute__((ext_vector_type(8))) short bf16x8;
typedef __attribute__((ext_vector_type(4))) float f32x4;

__device__ __forceinline__ float u16tof(u16 u){ return __uint_as_float(((u32)u) << 16); }
__device__ __forceinline__ float lo16(u32 v){ return __uint_as_float(v << 16); }
__device__ __forceinline__ float hi16(u32 v){ return __uint_as_float(v & 0xffff0000u); }
__device__ __forceinline__ u16 ftobf(float f){
  u32 b = __float_as_uint(f);
  return (u16)((b + 0x7FFFu + ((b >> 16) & 1u)) >> 16);
}
__device__ __forceinline__ u32 pack2(float a, float b){
  return (u32)ftobf(a) | ((u32)ftobf(b) << 16);
}
__device__ __forceinline__ float ldf(const void* p, int i, int isbf){
  return isbf ? u16tof(((const u16*)p)[i]) : ((const float*)p)[i];
}

__device__ __forceinline__ void acc8(float* a, uint4 v, float mk){
  a[0] = fmaf(lo16(v.x), mk, a[0]);
  a[1] = fmaf(hi16(v.x), mk, a[1]);
  a[2] = fmaf(lo16(v.y), mk, a[2]);
  a[3] = fmaf(hi16(v.y), mk, a[3]);
  a[4] = fmaf(lo16(v.z), mk, a[4]);
  a[5] = fmaf(hi16(v.z), mk, a[5]);
  a[6] = fmaf(lo16(v.w), mk, a[6]);
  a[7] = fmaf(hi16(v.w), mk, a[7]);
}

// async global->LDS, 16B per lane. Global src is PER-LANE; LDS dst is wave-uniform
// base + lane*16 (hardware rule). Counted by vmcnt, costs no VGPRs.
__device__ __forceinline__ void async16(const u16* g, const u16* l){
  __builtin_amdgcn_global_load_lds(
      (const __attribute__((address_space(1))) u32*)(uintptr_t)g,
      (__attribute__((address_space(3))) u32*)(uintptr_t)l,
      16, 0, 0);
}

// ---- fused prep. Block ranges (blockIdx-uniform branch):
//  [0, L] weights; [L+1, +goffB) goff; [histStart, +256) hist matrix (LDS atomics) ----
__global__ __launch_bounds__(256) void k_prep(const void* __restrict__ gw, const void* __restrict__ l1w,
                                              u16* __restrict__ Wf, int L, int goffB,
                                              const int* __restrict__ batch, int* __restrict__ goff,
                                              int N, int G,
                                              const int* __restrict__ dst, int* __restrict__ hist,
                                              int nE, int chunk, int* __restrict__ flag){
  __shared__ int sh[256];
  const int b = blockIdx.x;
  const int t = threadIdx.x;
  const int histStart = L + 1 + goffB;

  if (b >= histStart){                       // ---- per-chunk LDS histogram -> hist matrix
    sh[t] = 0; __syncthreads();
    const int blk = b - histStart;
    const int e0 = blk * chunk, e1 = min(e0 + chunk, nE);
    for (int e = e0 + t; e < e1; e += 256) atomicAdd(&sh[dst[e] >> 9], 1);
    __syncthreads();
    hist[blk * 256 + t] = sh[t];
    return;
  }
  if (b >= L + 1){                           // ---- goff build
    const int i = (b - (L + 1)) * 256 + t;
    if (i >= N) return;
    const int bt = batch[i];
    const int prev = (i == 0) ? -1 : batch[i - 1];
    for (int g = prev + 1; g <= bt; ++g) goff[g] = i;
    if (i == N - 1){ for (int g = bt + 1; g <= G; ++g) goff[g] = N; }
    return;
  }
  // ---- weight prep (full dtype detect)
  if (t == 0) sh[0] = 0;
  __syncthreads();
  int local = 0;
  for (int i = t; i < 4096; i += 256){
    u32 e = (((const u32*)gw)[i] >> 7) & 0xFFu;
    if (e >= 100u && e < 127u) local++;
  }
  atomicAdd(&sh[0], local);
  __syncthreads();
  const int isbf = (sh[0] > 2048) ? 1 : 0;
  if (b == 0 && t == 0) *flag = isbf;

  const void* src = (b < L) ? gw : l1w;
  const int sbase = (b < L) ? b * 16384 : 0;
  u16* dstp = Wf + (size_t)b * 16384;
  for (int g = t; g < 2048; g += 256){
    const int tt = g >> 8, ks = (g >> 6) & 3, lane = g & 63;
    const int n = tt * 16 + (lane & 15);
    const int k0 = ks * 32 + ((lane >> 4) << 3);
    u16* d = dstp + (size_t)g * 8;
    #pragma unroll
    for (int j = 0; j < 8; ++j){
      d[j] = ftobf(ldf(src, sbase + (k0 + j) * 128 + n, isbf));
    }
  }
}

// ---- parallel column-scan: block b = bucket. Exclusive prefix over chunks,
//      bucket total -> bsum. Replaces the serial 1-block hscan. ----
__global__ __launch_bounds__(256) void k_hsum(int* __restrict__ hist, int* __restrict__ bsum){
  __shared__ int sm[256];
  const int b = blockIdx.x;   // bucket
  const int t = threadIdx.x;  // chunk
  const int v = hist[t * 256 + b];
  sm[t] = v; __syncthreads();
  for (int off = 1; off < 256; off <<= 1){
    int a = (t >= off) ? sm[t - off] : 0;
    __syncthreads();
    sm[t] += a;
    __syncthreads();
  }
  hist[t * 256 + b] = sm[t] - v;   // exclusive prefix within bucket
  if (t == 255) bsum[b] = sm[255];
}

// ---- scatter edges to bucket-sorted tmpe (bucket bases re-derived inline) ----
__global__ __launch_bounds__(256) void k_scatter(const int* __restrict__ src, const int* __restrict__ dst,
                                                 const int* __restrict__ hist, const int* __restrict__ bsum,
                                                 int2* __restrict__ tmpe, int nE, int chunk){
  __shared__ int sm[256];
  __shared__ int base[256];
  const int blk = blockIdx.x, t = threadIdx.x;
  const int v = bsum[t];
  sm[t] = v; __syncthreads();
  for (int off = 1; off < 256; off <<= 1){
    int a = (t >= off) ? sm[t - off] : 0;
    __syncthreads();
    sm[t] += a;
    __syncthreads();
  }
  base[t] = (sm[t] - v) + hist[blk * 256 + t];
  __syncthreads();
  const int e0 = blk * chunk, e1 = min(e0 + chunk, nE);
  for (int e = e0 + t; e < e1; e += 256){
    const int d = dst[e];
    const int pos = atomicAdd(&base[d >> 9], 1);
    tmpe[pos] = make_int2(src[e], d);
  }
}

// ---- per-bucket local counting sort: boff, dinv, eid (bucket bounds inline) ----
__global__ __launch_bounds__(256) void k_local(const int2* __restrict__ tmpe, const int* __restrict__ bsum,
                                               int* __restrict__ boff, int* __restrict__ eid,
                                               float* __restrict__ dinv, int N, int nE, int nbkt){
  __shared__ int sm[256];
  __shared__ int bbx[257];
  __shared__ int hcnt[512];
  __shared__ int hoff[512];
  const int b = blockIdx.x, t = threadIdx.x;
  {
    const int v = bsum[t];
    sm[t] = v; __syncthreads();
    for (int off = 1; off < 256; off <<= 1){
      int a = (t >= off) ? sm[t - off] : 0;
      __syncthreads();
      sm[t] += a;
      __syncthreads();
    }
    bbx[t] = sm[t] - v;
    if (t == 255) bbx[256] = sm[255];
  }
  __syncthreads();
  const int n0 = b << 9;
  const int n1 = min(n0 + 512, N);
  const int nn = n1 - n0;
  const int e0 = bbx[b], e1 = bbx[b + 1];
  hcnt[t] = 0; hcnt[t + 256] = 0;
  __syncthreads();
  for (int e = e0 + t; e < e1; e += 256) atomicAdd(&hcnt[tmpe[e].y - n0], 1);
  __syncthreads();
  const int v0 = hcnt[t], v1 = hcnt[t + 256];
  hoff[t] = v0; hoff[t + 256] = v1;
  __syncthreads();
  for (int off = 1; off < 512; off <<= 1){
    int a0 = (t >= off) ? hoff[t - off] : 0;
    int a1 = (t + 256 >= off) ? hoff[t + 256 - off] : 0;
    __syncthreads();
    hoff[t] += a0; hoff[t + 256] += a1;
    __syncthreads();
  }
  const int ex0 = hoff[t] - v0 + e0;
  const int ex1 = hoff[t + 256] - v1 + e0;
  if (t < nn){       boff[n0 + t] = ex0;        dinv[n0 + t] = rsqrtf((float)v0 + 1.0f); }
  if (t + 256 < nn){ boff[n0 + t + 256] = ex1;  dinv[n0 + t + 256] = rsqrtf((float)v1 + 1.0f); }
  if (b == nbkt - 1 && t == 0) boff[N] = nE;
  __syncthreads();
  hoff[t] = ex0; hoff[t + 256] = ex1;
  __syncthreads();
  for (int e = e0 + t; e < e1; e += 256){
    const int2 pr = tmpe[e];
    const int pos = atomicAdd(&hoff[pr.y - n0], 1);
    eid[pos] = pr.x;
  }
}

// ---- dense matmul: T = (A @ W) * dinv, bf16 out (64 rows/block, W in LDS).
//      cvtin=1: A may be fp32 (when *fl==0) -> convert in-register (no cvt pass). ----
__global__ __launch_bounds__(256) void k_mm(const void* __restrict__ X, const u16* __restrict__ Wf,
                                            const float* __restrict__ dinv, u16* __restrict__ T,
                                            int n, int cvtin, const int* __restrict__ fl){
  __shared__ u16 smw[16384];
  const int isbf = *fl;
  const int fp32in = cvtin && !isbf;
  {
    const uint4* s = (const uint4*)Wf;
    uint4* d = (uint4*)smw;
    for (int i = threadIdx.x; i < 2048; i += 256) d[i] = s[i];
  }
  __syncthreads();

  const int wave = threadIdx.x >> 6, lane = threadIdx.x & 63;
  const int m0 = blockIdx.x * 64 + wave * 16;
  int arow = m0 + (lane & 15); if (arow > n - 1) arow = n - 1;
  const int koff = (lane >> 4) << 3;

  f32x4 acc[8];
  #pragma unroll
  for (int t = 0; t < 8; ++t) acc[t] = (f32x4){0.f, 0.f, 0.f, 0.f};

  #pragma unroll
  for (int ks = 0; ks < 4; ++ks){
    bf16x8 a;
    if (fp32in){
      const float* ap = (const float*)X + (size_t)arow * 128 + koff + ks * 32;
      const float4 f0 = *(const float4*)ap;
      const float4 f1 = *(const float4*)(ap + 4);
      a = (bf16x8){(short)ftobf(f0.x), (short)ftobf(f0.y), (short)ftobf(f0.z), (short)ftobf(f0.w),
                   (short)ftobf(f1.x), (short)ftobf(f1.y), (short)ftobf(f1.z), (short)ftobf(f1.w)};
    } else {
      a = *(const bf16x8*)((const u16*)X + (size_t)arow * 128 + koff + ks * 32);
    }
    #pragma unroll
    for (int t = 0; t < 8; ++t){
      const bf16x8 b = *(const bf16x8*)(smw + (size_t)(((t * 4 + ks) * 64 + lane) * 8));
      acc[t] = __builtin_amdgcn_mfma_f32_16x16x32_bf16(a, b, acc[t], 0, 0, 0);
    }
  }
  __syncthreads();

  const int quad = lane >> 4, col0 = lane & 15;
  float dv[4];
  #pragma unroll
  for (int r = 0; r < 4; ++r){
    const int row = m0 + quad * 4 + r;
    dv[r] = (row < n) ? dinv[row] : 0.f;
  }
  u16* my = smw + wave * 2112;
  #pragma unroll
  for (int t = 0; t < 8; ++t){
    #pragma unroll
    for (int r = 0; r < 4; ++r){
      my[(quad * 4 + r) * 132 + t * 16 + col0] = ftobf(acc[t][r] * dv[r]);
    }
  }
  #pragma unroll
  for (int i = 0; i < 4; ++i){
    const int row = i * 4 + (lane >> 4);
    const int grow = m0 + row;
    const int c8 = (lane & 15) * 8;
    if (grow < n){
      const u16* s = &my[row * 132 + c8];
      uint2 lo = *(const uint2*)(s);
      uint2 hi = *(const uint2*)(s + 4);
      *(uint4*)&T[(size_t)grow * 128 + c8] = make_uint4(lo.x, lo.y, hi.x, hi.y);
    }
  }
}

// ---- FUSED gather + next matmul (R5 champion), 16 nodes/block, 256 threads.
//      eid slice in LDS; LDS-ring async gather; counted vmcnt. ----
__global__ __launch_bounds__(256) void k_gmm(const u16* __restrict__ Tin, const int* __restrict__ boff,
                                             const int* __restrict__ eid, const float* __restrict__ dinv,
                                             const void* __restrict__ bias, int layer,
                                             const u16* __restrict__ Wf, u16* __restrict__ Tout,
                                             int n, const int* __restrict__ fl){
  __shared__ u16 sma[16 * 132];
  __shared__ u16 ring[4][4][512];   // [wave][slot][1KB]
  __shared__ int seid[1024];
  __shared__ int sboff[17];
  const int isbf = *fl;
  const int tid = threadIdx.x;
  const int wave = tid >> 6, lane = tid & 63;
  const int sub = lane >> 4, l16 = lane & 15;
  const int m0 = blockIdx.x * 16;

  const int e0 = boff[m0];
  const int e1 = boff[min(m0 + 16, n)];
  const int len = e1 - e0;
  const int inlds = (len <= 1024);
  if (tid < 17) sboff[tid] = boff[min(m0 + tid, n)];
  if (inlds){ for (int i = tid; i < len; i += 256) seid[i] = eid[e0 + i]; }
  __syncthreads();

  const int wsub = wave * 4 + sub;
  const int node = m0 + wsub;
  const int js = sboff[wsub];
  const int d  = sboff[wsub + 1] - js;

  float a[8];
  #pragma unroll
  for (int k = 0; k < 8; ++k) a[k] = 0.f;
  if (node < n){
    const uint4 sv = ((const uint4*)(Tin + (size_t)node * 128))[l16];
    acc8(a, sv, 1.f);
  }

  int T = 0;
  #pragma unroll
  for (int s2 = 0; s2 < 4; ++s2){
    const int dd = sboff[wave * 4 + s2 + 1] - sboff[wave * 4 + s2];
    T = (dd > T) ? dd : T;
  }

  if (inlds){
    const int jloc = js - e0;
    const int jlast = jloc + ((d > 0) ? (d - 1) : 0);
    const u16* base = Tin + (size_t)l16 * 8;
    u16* slot = &ring[wave][0][0];
    #pragma unroll
    for (int t = 0; t < 4; ++t){
      if (t < T){
        const int idx = (d > 0) ? seid[(t < d) ? (jloc + t) : jlast] : 0;
        async16(base + (size_t)idx * 128, slot + (t & 3) * 512);
      }
    }
    int t = 0;
    for (; t + 4 <= T; ++t){
      asm volatile("s_waitcnt vmcnt(3)" ::: "memory");
      const uint4 v = *(const uint4*)(slot + (t & 3) * 512 + lane * 8);
      acc8(a, v, (t < d) ? 1.f : 0.f);
      const int tn = t + 4;
      if (tn < T){
        const int idx = (d > 0) ? seid[(tn < d) ? (jloc + tn) : jlast] : 0;
        async16(base + (size_t)idx * 128, slot + (tn & 3) * 512);
      }
    }
    for (; t < T; ++t){
      const int rem = T - t - 1;
      if (rem >= 2)      asm volatile("s_waitcnt vmcnt(2)" ::: "memory");
      else if (rem == 1) asm volatile("s_waitcnt vmcnt(1)" ::: "memory");
      else               asm volatile("s_waitcnt vmcnt(0)" ::: "memory");
      const uint4 v = *(const uint4*)(slot + (t & 3) * 512 + lane * 8);
      acc8(a, v, (t < d) ? 1.f : 0.f);
    }
  } else {
    for (int j = js; j < js + d; ++j){
      const uint4 v = ((const uint4*)(Tin + (size_t)eid[j] * 128))[l16];
      acc8(a, v, 1.f);
    }
  }

  float h[8];
  #pragma unroll
  for (int k = 0; k < 8; ++k) h[k] = 0.f;
  if (node < n){
    const float di = dinv[node];
    const int bb = layer * 128 + l16 * 8;
    #pragma unroll
    for (int k = 0; k < 8; ++k){
      h[k] = fmaxf(fmaf(a[k], di, ldf(bias, bb + k, isbf)), 0.f);
    }
  }
  {
    uint4 o;
    o.x = pack2(h[0], h[1]); o.y = pack2(h[2], h[3]); o.z = pack2(h[4], h[5]); o.w = pack2(h[6], h[7]);
    *(uint4*)&sma[(wave * 4 + sub) * 132 + l16 * 8] = o;
  }
  __syncthreads();

  f32x4 acc[2];
  acc[0] = (f32x4){0.f,0.f,0.f,0.f}; acc[1] = (f32x4){0.f,0.f,0.f,0.f};
  #pragma unroll
  for (int ks = 0; ks < 4; ++ks){
    const bf16x8 av = *(const bf16x8*)(sma + l16 * 132 + sub * 8 + ks * 32);
    #pragma unroll
    for (int tt = 0; tt < 2; ++tt){
      const int t = wave * 2 + tt;
      const bf16x8 bv = *(const bf16x8*)(Wf + (size_t)(((t * 4 + ks) * 64 + lane) * 8));
      acc[tt] = __builtin_amdgcn_mfma_f32_16x16x32_bf16(av, bv, acc[tt], 0, 0, 0);
    }
  }
  __syncthreads();

  float dv[4];
  #pragma unroll
  for (int r = 0; r < 4; ++r){
    const int row = m0 + sub * 4 + r;
    dv[r] = (row < n) ? dinv[row] : 0.f;
  }
  #pragma unroll
  for (int tt = 0; tt < 2; ++tt){
    const int t = wave * 2 + tt;
    #pragma unroll
    for (int r = 0; r < 4; ++r){
      sma[(sub * 4 + r) * 132 + t * 16 + l16] = ftobf(acc[tt][r] * dv[r]);
    }
  }
  __syncthreads();

  {
    const int row = tid >> 4;
    const int c8 = (tid & 15) * 8;
    if (m0 + row < n){
      const u16* s = &sma[row * 132 + c8];
      uint2 lo = *(const uint2*)(s);
      uint2 hi = *(const uint2*)(s + 4);
      *(uint4*)&Tout[(size_t)(m0 + row) * 128 + c8] = make_uint4(lo.x, lo.y, hi.x, hi.y);
    }
  }
}

// ---- FUSED gather + MLP head (R5 champion), 16 nodes/block, 256 threads ----
__global__ __launch_bounds__(256) void k_ghead(const u16* __restrict__ Tin, const int* __restrict__ boff,
                                               const int* __restrict__ eid, const float* __restrict__ dinv,
                                               const void* __restrict__ bias, int layer,
                                               const u16* __restrict__ Wf, const void* __restrict__ b1,
                                               const void* __restrict__ w2, const void* __restrict__ b2,
                                               const int* __restrict__ mask, float* __restrict__ s,
                                               int n, const int* __restrict__ fl){
  __shared__ u16 sma[16 * 132];
  __shared__ u16 ring[4][4][512];
  __shared__ int seid[1024];
  __shared__ int sboff[17];
  __shared__ float sred[4][16];
  const int isbf = *fl;
  const int tid = threadIdx.x;
  const int wave = tid >> 6, lane = tid & 63;
  const int sub = lane >> 4, l16 = lane & 15;
  const int m0 = blockIdx.x * 16;

  const int e0 = boff[m0];
  const int e1 = boff[min(m0 + 16, n)];
  const int len = e1 - e0;
  const int inlds = (len <= 1024);
  if (tid < 17) sboff[tid] = boff[min(m0 + tid, n)];
  if (inlds){ for (int i = tid; i < len; i += 256) seid[i] = eid[e0 + i]; }
  __syncthreads();

  const int wsub = wave * 4 + sub;
  const int node = m0 + wsub;
  const int js = sboff[wsub];
  const int d  = sboff[wsub + 1] - js;

  float a[8];
  #pragma unroll
  for (int k = 0; k < 8; ++k) a[k] = 0.f;
  if (node < n){
    const uint4 sv = ((const uint4*)(Tin + (size_t)node * 128))[l16];
    acc8(a, sv, 1.f);
  }

  int T = 0;
  #pragma unroll
  for (int s2 = 0; s2 < 4; ++s2){
    const int dd = sboff[wave * 4 + s2 + 1] - sboff[wave * 4 + s2];
    T = (dd > T) ? dd : T;
  }

  if (inlds){
    const int jloc = js - e0;
    const int jlast = jloc + ((d > 0) ? (d - 1) : 0);
    const u16* base = Tin + (size_t)l16 * 8;
    u16* slot = &ring[wave][0][0];
    #pragma unroll
    for (int t = 0; t < 4; ++t){
      if (t < T){
        const int idx = (d > 0) ? seid[(t < d) ? (jloc + t) : jlast] : 0;
        async16(base + (size_t)idx * 128, slot + (t & 3) * 512);
      }
    }
    int t = 0;
    for (; t + 4 <= T; ++t){
      asm volatile("s_waitcnt vmcnt(3)" ::: "memory");
      const uint4 v = *(const uint4*)(slot + (t & 3) * 512 + lane * 8);
      acc8(a, v, (t < d) ? 1.f : 0.f);
      const int tn = t + 4;
      if (tn < T){
        const int idx = (d > 0) ? seid[(tn < d) ? (jloc + tn) : jlast] : 0;
        async16(base + (size_t)idx * 128, slot + (tn & 3) * 512);
      }
    }
    for (; t < T; ++t){
      const int rem = T - t - 1;
      if (rem >= 2)      asm volatile("s_waitcnt vmcnt(2)" ::: "memory");
      else if (rem == 1) asm volatile("s_waitcnt vmcnt(1)" ::: "memory");
      else               asm volatile("s_waitcnt vmcnt(0)" ::: "memory");
      const uint4 v = *(const uint4*)(slot + (t & 3) * 512 + lane * 8);
      acc8(a, v, (t < d) ? 1.f : 0.f);
    }
  } else {
    for (int j = js; j < js + d; ++j){
      const uint4 v = ((const uint4*)(Tin + (size_t)eid[j] * 128))[l16];
      acc8(a, v, 1.f);
    }
  }

  float h[8];
  #pragma unroll
  for (int k = 0; k < 8; ++k) h[k] = 0.f;
  if (node < n){
    const float di = dinv[node];
    const int bb = layer * 128 + l16 * 8;
    #pragma unroll
    for (int k = 0; k < 8; ++k){
      h[k] = fmaf(a[k], di, ldf(bias, bb + k, isbf));
    }
  }
  {
    uint4 o;
    o.x = pack2(h[0], h[1]); o.y = pack2(h[2], h[3]); o.z = pack2(h[4], h[5]); o.w = pack2(h[6], h[7]);
    *(uint4*)&sma[(wave * 4 + sub) * 132 + l16 * 8] = o;
  }
  __syncthreads();

  f32x4 acc[2];
  acc[0] = (f32x4){0.f,0.f,0.f,0.f}; acc[1] = (f32x4){0.f,0.f,0.f,0.f};
  #pragma unroll
  for (int ks = 0; ks < 4; ++ks){
    const bf16x8 av = *(const bf16x8*)(sma + l16 * 132 + sub * 8 + ks * 32);
    #pragma unroll
    for (int tt = 0; tt < 2; ++tt){
      const int t = wave * 2 + tt;
      const bf16x8 bv = *(const bf16x8*)(Wf + (size_t)(((t * 4 + ks) * 64 + lane) * 8));
      acc[tt] = __builtin_amdgcn_mfma_f32_16x16x32_bf16(av, bv, acc[tt], 0, 0, 0);
    }
  }

  float p0 = 0.f, p1 = 0.f, p2 = 0.f, p3 = 0.f;
  #pragma unroll
  for (int tt = 0; tt < 2; ++tt){
    const int col = (wave * 2 + tt) * 16 + l16;
    const float bv = ldf(b1, col, isbf);
    const float wv = ldf(w2, col, isbf);
    p0 = fmaf(fmaxf(acc[tt][0] + bv, 0.f), wv, p0);
    p1 = fmaf(fmaxf(acc[tt][1] + bv, 0.f), wv, p1);
    p2 = fmaf(fmaxf(acc[tt][2] + bv, 0.f), wv, p2);
    p3 = fmaf(fmaxf(acc[tt][3] + bv, 0.f), wv, p3);
  }
  #pragma unroll
  for (int k = 1; k < 16; k <<= 1){
    p0 += __shfl_xor(p0, k);
    p1 += __shfl_xor(p1, k);
    p2 += __shfl_xor(p2, k);
    p3 += __shfl_xor(p3, k);
  }
  if (l16 == 0){
    sred[wave][sub * 4 + 0] = p0;
    sred[wave][sub * 4 + 1] = p1;
    sred[wave][sub * 4 + 2] = p2;
    sred[wave][sub * 4 + 3] = p3;
  }
  __syncthreads();
  if (tid < 16){
    const int row = m0 + tid;
    if (row < n){
      float sc = sred[0][tid] + sred[1][tid] + sred[2][tid] + sred[3][tid]
               + ldf(b2, 0, isbf);
      if (mask[row] == 0) sc = -1e9f;
      s[row] = sc;
    }
  }
}

// ---- per-graph softmax ----
__global__ __launch_bounds__(256) void k_gsm(const float* __restrict__ s, const int* __restrict__ goff,
                                             void* __restrict__ out, int G, const int* __restrict__ fl){
  const int g = blockIdx.x * 4 + (threadIdx.x >> 6);
  if (g >= G) return;
  const int lane = threadIdx.x & 63;
  const int i0 = goff[g], i1 = goff[g + 1];
  if (i0 >= i1) return;
  float m = -3.4e38f;
  for (int j = i0 + lane; j < i1; j += 64) m = fmaxf(m, s[j]);
  #pragma unroll
  for (int k = 32; k; k >>= 1) m = fmaxf(m, __shfl_xor(m, k));
  float zz = 0.f;
  for (int j = i0 + lane; j < i1; j += 64) zz += expf(s[j] - m);
  #pragma unroll
  for (int k = 32; k; k >>= 1) zz += __shfl_xor(zz, k);
  const float rz = 1.f / zz;
  const int isbf = *fl;
  for (int j = i0 + lane; j < i1; j += 64){
    const float v = expf(s[j] - m) * rz;
    if (isbf) ((u16*)out)[j] = ftobf(v);
    else      ((float*)out)[j] = v;
  }
}

extern "C" void kernel_launch(void* const* d_in, const int* in_sizes, int n_in,
                              void* d_out, int out_size, void* d_ws, size_t ws_size,
                              hipStream_t stream){
  const void* x    = d_in[0];
  const int* ei    = (const int*)d_in[1];
  const int* batch = (const int*)d_in[2];
  const int* mask  = (const int*)d_in[3];
  const void* gw   = d_in[4];
  const void* gb   = d_in[5];
  const void* l1w  = d_in[6];
  const void* l1b  = d_in[7];
  const void* l2w  = d_in[8];
  const void* l2b  = d_in[9];

  const int N = in_sizes[2];        // <= 131072 for the 512-node buckets (dst>>9)
  const int E = in_sizes[1] / 2;
  const int D = 128;
  const int L = in_sizes[4] / (D * D);
  const int G = 1000;   // from reference; not derivable from sizes

  char* p = (char*)d_ws;
  u16*  Hb    = (u16*)p;   p += (size_t)N * D * sizeof(u16);   // T ping
  u16*  Tb    = (u16*)p;   p += (size_t)N * D * sizeof(u16);   // T pong
  u16*  Wf    = (u16*)p;   p += (size_t)(L + 1) * D * D * sizeof(u16);
  float* dinv = (float*)p; p += (size_t)N * sizeof(float);
  float* sbuf = (float*)p; p += (size_t)N * sizeof(float);
  int*  boff  = (int*)p;   p += (size_t)(N + 1) * sizeof(int);
  int*  eid   = (int*)p;   p += (size_t)E * sizeof(int);
  int*  goff  = (int*)p;   p += (size_t)(G + 1) * sizeof(int);
  int*  hist  = (int*)p;   p += 256 * 256 * sizeof(int);
  int*  bsum  = (int*)p;   p += 256 * sizeof(int);
  int2* tmpe  = (int2*)p;  p += (size_t)E * sizeof(int2);
  int*  flag  = (int*)p;   p += 256;

  const int* srcp = ei;
  const int* dstp = ei + E;

  const int mmg   = (N + 63) / 64;
  const int fg    = (N + 15) / 16;
  const int goffB = (N + 255) / 256;
  const int chunk = (E + 255) / 256;
  const int nbkt  = (N + 511) / 512;

  // ---- prep: {weights | goff | hist}; parallel column scan; scatter; local sort ----
  k_prep<<<(L + 1) + goffB + 256, 256, 0, stream>>>(gw, l1w, Wf, L, goffB,
                                                    batch, goff, N, G, dstp, hist, E, chunk, flag);
  k_hsum<<<256, 256, 0, stream>>>(hist, bsum);
  k_scatter<<<256, 256, 0, stream>>>(srcp, dstp, hist, bsum, tmpe, E, chunk);
  k_local<<<nbkt, 256, 0, stream>>>(tmpe, bsum, boff, eid, dinv, N, E, nbkt);

  // ---- layer 0: T0 = (x @ W0)*dinv (reads fp32 x directly when needed) ----
  k_mm<<<mmg, 256, 0, stream>>>(x, Wf, dinv, Tb, N, 1, flag);
  // fused layers: gather(l) + mm(l+1)
  k_gmm<<<fg, 256, 0, stream>>>(Tb, boff, eid, dinv, gb, 0, Wf + (size_t)1 * D * D, Hb, N, flag);
  k_gmm<<<fg, 256, 0, stream>>>(Hb, boff, eid, dinv, gb, 1, Wf + (size_t)2 * D * D, Tb, N, flag);
  // fused final gather + MLP head
  k_ghead<<<fg, 256, 0, stream>>>(Tb, boff, eid, dinv, gb, 2, Wf + (size_t)L * D * D,
                                  l1b, l2w, l2b, mask, sbuf, N, flag);
  k_gsm<<<(G + 3) / 4, 256, 0, stream>>>(sbuf, goff, d_out, G, flag);
}